// Round 2
// baseline (608.307 us; speedup 1.0000x reference)
//
#include <hip/hip_runtime.h>

// GCN 2-layer: N=100000, F=128 -> H=16 (relu) -> C=40, E=3200000.
//
// R3: fix line-granular atomic serialization in the CSR build.
// Evidence: k_permute 270us @ VALUBusy 0.3%, HBM 10% -- packed cursor has 16
// nodes/64B line -> ~512 contended return-atomics per line at ~1265 cy each.
// Fix: pad cursor/counter to 1 node per 64B line (stride 16 ints). The 6.4MB
// padded array lives in d_out (free scratch until k_gather2, the only writer
// of out). Same padding applied to the histogram pass (same disease,
// fire-and-forget variant: ~780 cy/line-op).
//
// Math: norm(s->d) = dinv[s]*dinv[d], self-loop norm = dinv[n]^2.
//   h1p = (x@W1)*dinv            (pre-scaled => no dinv[src] gather per edge)
//   agg1[n] = dinv[n]*(h1p[n] + sum_{s in in(n)} h1p[s])
//   r1p[n]  = relu(agg1[n]+b1)*dinv[n]          (fused in gather1 epilogue)
//   agg2[n] = dinv[n]*(r1p[n] + sum r1p[s])
//   out[n]  = agg2[n]@W2 + b2                   (fused in gather2 epilogue)

#define N_NODES 100000
#define F_IN    128
#define H_MID   16
#define C_OUT   40
#define N_EDGES 3200000
#define NB      391          // ceil(N_NODES/256)
#define CPAD    16           // cursor padding: 16 ints = 64B = one line per node

__global__ void k_zero(int* __restrict__ cur) {
    int i = blockIdx.x * 256 + threadIdx.x;   // over N_NODES*CPAD = 1.6M
    cur[i] = 0;
}

__global__ void k_count(const int* __restrict__ dst, int* __restrict__ cur) {
    int e = blockIdx.x * 256 + threadIdx.x;
    if (e < N_EDGES) atomicAdd(&cur[dst[e] * CPAD], 1);
}

// block-local exclusive scan of counts -> rp, block sums -> part, dinv = rsqrt(1+cnt)
__global__ void __launch_bounds__(256) k_scan1(const int* __restrict__ cur,
                                               int* __restrict__ rp,
                                               int* __restrict__ part,
                                               float* __restrict__ dinv) {
    __shared__ int s[256];
    int t = threadIdx.x;
    int i = blockIdx.x * 256 + t;
    int v = (i < N_NODES) ? cur[i * CPAD] : 0;
    s[t] = v;
    __syncthreads();
    for (int off = 1; off < 256; off <<= 1) {
        int x = (t >= off) ? s[t - off] : 0;
        __syncthreads();
        s[t] += x;
        __syncthreads();
    }
    if (i < N_NODES) {
        rp[i] = s[t] - v;                       // exclusive (block-local)
        dinv[i] = rsqrtf(1.0f + (float)v);      // deg = indeg + self loop
    }
    if (t == 255) part[blockIdx.x] = s[255];
}

// exclusive scan of the NB block sums (single block)
__global__ void __launch_bounds__(512) k_scan2(int* __restrict__ part) {
    __shared__ int s[512];
    int t = threadIdx.x;
    int v = (t < NB) ? part[t] : 0;
    s[t] = v;
    __syncthreads();
    for (int off = 1; off < 512; off <<= 1) {
        int x = (t >= off) ? s[t - off] : 0;
        __syncthreads();
        s[t] += x;
        __syncthreads();
    }
    if (t < NB) part[t] = s[t] - v;
}

__global__ void k_scan3(int* __restrict__ rp, const int* __restrict__ part,
                        int* __restrict__ cur) {
    int i = blockIdx.x * 256 + threadIdx.x;
    if (i < N_NODES) {
        int v = rp[i] + part[blockIdx.x];
        rp[i] = v;
        cur[i * CPAD] = v;                      // padded cursor init
    }
    if (i == 0) rp[N_NODES] = N_EDGES;
}

// counting-sort edges by dst: es[pos] = src
__global__ void k_permute(const int* __restrict__ src, const int* __restrict__ dst,
                          int* __restrict__ cur, int* __restrict__ es) {
    int e = blockIdx.x * 256 + threadIdx.x;
    if (e < N_EDGES) {
        int d = dst[e];
        int pos = atomicAdd(&cur[d * CPAD], 1);
        es[pos] = src[e];
    }
}

// 16 nodes per block, 256 threads = 16 nodes x 16 out-features.
// h1p = (x@W1) * dinv[node]
__global__ void __launch_bounds__(256) k_gemm1(
    const float* __restrict__ x, const float* __restrict__ W1,
    const float* __restrict__ dinv, float* __restrict__ h1p) {
    __shared__ float w[F_IN * H_MID];   // 8 KB
    __shared__ float xs[16 * 132];      // padded rows: no 128-stride conflicts
    int t = threadIdx.x;
    for (int i = t; i < F_IN * H_MID; i += 256) w[i] = W1[i];
    int tile = blockIdx.x;              // 6250 tiles, exact
    const float4* xg = (const float4*)(x + (size_t)tile * 16 * F_IN);
    float4* xs4 = (float4*)xs;          // row stride 33 float4
    for (int i = t; i < 512; i += 256) {
        int r = i >> 5, c4 = i & 31;
        xs4[r * 33 + c4] = xg[r * 32 + c4];
    }
    __syncthreads();
    int node = t >> 4, j = t & 15;
    const float* xr = xs + node * 132;
    float acc = 0.f;
#pragma unroll 8
    for (int k = 0; k < F_IN; ++k) acc += xr[k] * w[k * H_MID + j];
    int g = tile * 16 + node;
    h1p[(size_t)g * H_MID + j] = acc * dinv[g];
}

// gather layer 1 + fused relu/bias/prescale:
// r1p[n] = relu(dinv[n]*(h1p[n] + sum h1p[s]) + b1) * dinv[n]
__global__ void __launch_bounds__(256) k_gather1(
    const int* __restrict__ rp, const int* __restrict__ es,
    const float* __restrict__ dinv, const float* __restrict__ h1p,
    const float* __restrict__ b1, float* __restrict__ r1p) {
    int t = threadIdx.x;
    int node = blockIdx.x * 16 + (t >> 4), j = t & 15;
    float dv = dinv[node];
    int beg = rp[node], end = rp[node + 1];
    float acc = h1p[(size_t)node * H_MID + j];    // self loop (pre-scaled)
    int e = beg;
    for (; e + 4 <= end; e += 4) {
        int s0 = es[e], s1 = es[e + 1], s2 = es[e + 2], s3 = es[e + 3];
        float v0 = h1p[(size_t)s0 * H_MID + j];
        float v1 = h1p[(size_t)s1 * H_MID + j];
        float v2 = h1p[(size_t)s2 * H_MID + j];
        float v3 = h1p[(size_t)s3 * H_MID + j];
        acc += v0 + v1 + v2 + v3;
    }
    for (; e < end; ++e) acc += h1p[(size_t)es[e] * H_MID + j];
    float agg1 = dv * acc;
    r1p[(size_t)node * H_MID + j] = fmaxf(agg1 + b1[j], 0.f) * dv;
}

// gather layer 2 + fused @W2 + b2 epilogue (LDS).
__global__ void __launch_bounds__(256) k_gather2(
    const int* __restrict__ rp, const int* __restrict__ es,
    const float* __restrict__ dinv, const float* __restrict__ r1p,
    const float* __restrict__ W2, const float* __restrict__ b2,
    float* __restrict__ out) {
    __shared__ float w2[H_MID * C_OUT];   // 640
    __shared__ float a2[16 * 17];         // padded
    int t = threadIdx.x;
    for (int i = t; i < H_MID * C_OUT; i += 256) w2[i] = W2[i];
    int tile = blockIdx.x;
    int node = tile * 16 + (t >> 4), j = t & 15;
    float dv = dinv[node];
    int beg = rp[node], end = rp[node + 1];
    float acc = r1p[(size_t)node * H_MID + j];    // self loop (pre-scaled)
    int e = beg;
    for (; e + 4 <= end; e += 4) {
        int s0 = es[e], s1 = es[e + 1], s2 = es[e + 2], s3 = es[e + 3];
        float v0 = r1p[(size_t)s0 * H_MID + j];
        float v1 = r1p[(size_t)s1 * H_MID + j];
        float v2 = r1p[(size_t)s2 * H_MID + j];
        float v3 = r1p[(size_t)s3 * H_MID + j];
        acc += v0 + v1 + v2 + v3;
    }
    for (; e < end; ++e) acc += r1p[(size_t)es[e] * H_MID + j];
    a2[(t >> 4) * 17 + j] = dv * acc;
    __syncthreads();
    for (int idx = t; idx < 16 * C_OUT; idx += 256) {
        int nd = idx / C_OUT, c = idx % C_OUT;
        float s = b2[c];
#pragma unroll
        for (int jj = 0; jj < H_MID; ++jj) s += a2[nd * 17 + jj] * w2[jj * C_OUT + c];
        out[((size_t)tile * 16 + nd) * C_OUT + c] = s;
    }
}

extern "C" void kernel_launch(void* const* d_in, const int* in_sizes, int n_in,
                              void* d_out, int out_size, void* d_ws, size_t ws_size,
                              hipStream_t stream) {
    const float* x  = (const float*)d_in[0];
    const int*   ei = (const int*)d_in[1];     // [2, E]: row 0 = src, row 1 = dst
    const float* W1 = (const float*)d_in[2];
    const float* b1 = (const float*)d_in[3];
    const float* W2 = (const float*)d_in[4];
    const float* b2 = (const float*)d_in[5];
    float* out = (float*)d_out;

    const int* src = ei;
    const int* dst = ei + N_EDGES;

    // ws layout (4B units):
    //   rp[100352] | part[1024] | dinv[100352] | es[3.2M] | h1p[1.6M] | r1p[1.6M]
    //   ~= 26.4 MiB.
    // Padded cursor (N*CPAD = 1.6M ints = 6.4MB) lives in d_out (16MB): free
    // scratch until k_gather2, which is the sole writer of out and does not
    // read the cursor.
    int* rp     = (int*)d_ws;
    int* part   = rp + 100352;
    float* dinv = (float*)(part + 1024);
    int* es     = (int*)(dinv + 100352);
    float* h1p  = (float*)(es + N_EDGES);
    float* r1p  = h1p + (size_t)N_NODES * H_MID;
    int* cur    = (int*)d_out;            // N_NODES*CPAD ints = 6.4MB <= 16MB

    const int B = 256;
    const int EB = (N_EDGES + B - 1) / B;     // 12500

    k_zero<<<(N_NODES * CPAD) / B, B, 0, stream>>>(cur);   // 6250 blocks exact
    k_count<<<EB, B, 0, stream>>>(dst, cur);
    k_scan1<<<NB, B, 0, stream>>>(cur, rp, part, dinv);
    k_scan2<<<1, 512, 0, stream>>>(part);
    k_scan3<<<NB, B, 0, stream>>>(rp, part, cur);
    k_gemm1<<<N_NODES / 16, B, 0, stream>>>(x, W1, dinv, h1p);
    k_permute<<<EB, B, 0, stream>>>(src, dst, cur, es);
    k_gather1<<<N_NODES / 16, B, 0, stream>>>(rp, es, dinv, h1p, b1, r1p);
    k_gather2<<<N_NODES / 16, B, 0, stream>>>(rp, es, dinv, r1p, W2, b2, out);
}

// Round 3
// 424.679 us; speedup vs baseline: 1.4324x; 1.4324x over previous
//
#include <hip/hip_runtime.h>

// GCN 2-layer: N=100000, F=128 -> H=16 (relu) -> C=40, E=3200000.
//
// R4: attack the return-atomic latency chain in the CSR build.
// Evidence: R3's cursor padding changed nothing (270->287us, noise) -- so the
// permute is NOT line-contention-bound. It is latency x in-flight bound:
// each wave had ONE return-atomic in flight, then stalled on vmcnt before the
// dependent scattered store (11 Gops/s ~= 64 outstanding/CU / 1.4us RTT).
// Fix: (a) merge count+rank into one pass (atomicAdd return value IS the
// rank, stored coalesced) -- halves total atomics and makes the permute
// atomic-free; (b) 8-edge ILP batching so each thread keeps 8 independent
// memory ops in flight.
//
// Math: norm(s->d) = dinv[s]*dinv[d], self-loop norm = dinv[n]^2.
//   h1p = (x@W1)*dinv            (pre-scaled => no dinv[src] gather per edge)
//   agg1[n] = dinv[n]*(h1p[n] + sum_{s in in(n)} h1p[s])
//   r1p[n]  = relu(agg1[n]+b1)*dinv[n]          (fused in gather1 epilogue)
//   agg2[n] = dinv[n]*(r1p[n] + sum r1p[s])
//   out[n]  = agg2[n]@W2 + b2                   (fused in gather2 epilogue)

#define N_NODES 100000
#define F_IN    128
#define H_MID   16
#define C_OUT   40
#define N_EDGES 3200000
#define NB      391          // ceil(N_NODES/256)
#define CPAD    4            // cnt padding: 4 ints -> 4 nodes per 64B line
#define EPT     8            // edges per thread in edge passes
#define G_EDGE  (N_EDGES / EPT)   // 400000 threads, exact

__global__ void k_zero(int* __restrict__ cnt) {
    int i = blockIdx.x * 256 + threadIdx.x;   // over 100352*CPAD = 401408 = 1568*256
    cnt[i] = 0;
}

// Fused histogram + rank: rank[e] = old count of dst[e]. 8 independent
// return-atomics in flight per thread; rank store is coalesced.
__global__ void __launch_bounds__(256) k_count_rank(
    const int* __restrict__ dst, int* __restrict__ cnt, int* __restrict__ rank) {
    int tid = blockIdx.x * 256 + threadIdx.x;
    if (tid >= G_EDGE) return;
    int d[EPT], r[EPT];
#pragma unroll
    for (int k = 0; k < EPT; ++k) d[k] = dst[tid + k * G_EDGE];
#pragma unroll
    for (int k = 0; k < EPT; ++k) r[k] = atomicAdd(&cnt[d[k] * CPAD], 1);
#pragma unroll
    for (int k = 0; k < EPT; ++k) rank[tid + k * G_EDGE] = r[k];
}

// block-local exclusive scan of counts -> rp, block sums -> part, dinv = rsqrt(1+cnt)
__global__ void __launch_bounds__(256) k_scan1(const int* __restrict__ cnt,
                                               int* __restrict__ rp,
                                               int* __restrict__ part,
                                               float* __restrict__ dinv) {
    __shared__ int s[256];
    int t = threadIdx.x;
    int i = blockIdx.x * 256 + t;
    int v = (i < N_NODES) ? cnt[i * CPAD] : 0;
    s[t] = v;
    __syncthreads();
    for (int off = 1; off < 256; off <<= 1) {
        int x = (t >= off) ? s[t - off] : 0;
        __syncthreads();
        s[t] += x;
        __syncthreads();
    }
    if (i < N_NODES) {
        rp[i] = s[t] - v;                       // exclusive (block-local)
        dinv[i] = rsqrtf(1.0f + (float)v);      // deg = indeg + self loop
    }
    if (t == 255) part[blockIdx.x] = s[255];
}

// exclusive scan of the NB block sums (single block)
__global__ void __launch_bounds__(512) k_scan2(int* __restrict__ part) {
    __shared__ int s[512];
    int t = threadIdx.x;
    int v = (t < NB) ? part[t] : 0;
    s[t] = v;
    __syncthreads();
    for (int off = 1; off < 512; off <<= 1) {
        int x = (t >= off) ? s[t - off] : 0;
        __syncthreads();
        s[t] += x;
        __syncthreads();
    }
    if (t < NB) part[t] = s[t] - v;
}

__global__ void k_scan3(int* __restrict__ rp, const int* __restrict__ part) {
    int i = blockIdx.x * 256 + threadIdx.x;
    if (i < N_NODES) rp[i] += part[blockIdx.x];
    if (i == 0) rp[N_NODES] = N_EDGES;
}

// counting-sort edges by dst, atomic-free: es[rp[d] + rank[e]] = src[e].
// Only random READ is rp (400KB, L2-resident); 8 gathers in flight.
__global__ void __launch_bounds__(256) k_permute(
    const int* __restrict__ src, const int* __restrict__ dst,
    const int* __restrict__ rank, const int* __restrict__ rp,
    int* __restrict__ es) {
    int tid = blockIdx.x * 256 + threadIdx.x;
    if (tid >= G_EDGE) return;
    int d[EPT], r[EPT], s[EPT], p[EPT];
#pragma unroll
    for (int k = 0; k < EPT; ++k) d[k] = dst[tid + k * G_EDGE];
#pragma unroll
    for (int k = 0; k < EPT; ++k) r[k] = rank[tid + k * G_EDGE];
#pragma unroll
    for (int k = 0; k < EPT; ++k) s[k] = src[tid + k * G_EDGE];
#pragma unroll
    for (int k = 0; k < EPT; ++k) p[k] = rp[d[k]] + r[k];
#pragma unroll
    for (int k = 0; k < EPT; ++k) es[p[k]] = s[k];
}

// 16 nodes per block, 256 threads = 16 nodes x 16 out-features.
// h1p = (x@W1) * dinv[node]
__global__ void __launch_bounds__(256) k_gemm1(
    const float* __restrict__ x, const float* __restrict__ W1,
    const float* __restrict__ dinv, float* __restrict__ h1p) {
    __shared__ float w[F_IN * H_MID];   // 8 KB
    __shared__ float xs[16 * 132];      // padded rows: no 128-stride conflicts
    int t = threadIdx.x;
    for (int i = t; i < F_IN * H_MID; i += 256) w[i] = W1[i];
    int tile = blockIdx.x;              // 6250 tiles, exact
    const float4* xg = (const float4*)(x + (size_t)tile * 16 * F_IN);
    float4* xs4 = (float4*)xs;          // row stride 33 float4
    for (int i = t; i < 512; i += 256) {
        int r = i >> 5, c4 = i & 31;
        xs4[r * 33 + c4] = xg[r * 32 + c4];
    }
    __syncthreads();
    int node = t >> 4, j = t & 15;
    const float* xr = xs + node * 132;
    float acc = 0.f;
#pragma unroll 8
    for (int k = 0; k < F_IN; ++k) acc += xr[k] * w[k * H_MID + j];
    int g = tile * 16 + node;
    h1p[(size_t)g * H_MID + j] = acc * dinv[g];
}

// gather layer 1 + fused relu/bias/prescale:
// r1p[n] = relu(dinv[n]*(h1p[n] + sum h1p[s]) + b1) * dinv[n]
__global__ void __launch_bounds__(256) k_gather1(
    const int* __restrict__ rp, const int* __restrict__ es,
    const float* __restrict__ dinv, const float* __restrict__ h1p,
    const float* __restrict__ b1, float* __restrict__ r1p) {
    int t = threadIdx.x;
    int node = blockIdx.x * 16 + (t >> 4), j = t & 15;
    float dv = dinv[node];
    int beg = rp[node], end = rp[node + 1];
    float acc = h1p[(size_t)node * H_MID + j];    // self loop (pre-scaled)
    int e = beg;
    for (; e + 4 <= end; e += 4) {
        int s0 = es[e], s1 = es[e + 1], s2 = es[e + 2], s3 = es[e + 3];
        float v0 = h1p[(size_t)s0 * H_MID + j];
        float v1 = h1p[(size_t)s1 * H_MID + j];
        float v2 = h1p[(size_t)s2 * H_MID + j];
        float v3 = h1p[(size_t)s3 * H_MID + j];
        acc += v0 + v1 + v2 + v3;
    }
    for (; e < end; ++e) acc += h1p[(size_t)es[e] * H_MID + j];
    float agg1 = dv * acc;
    r1p[(size_t)node * H_MID + j] = fmaxf(agg1 + b1[j], 0.f) * dv;
}

// gather layer 2 + fused @W2 + b2 epilogue (LDS).
__global__ void __launch_bounds__(256) k_gather2(
    const int* __restrict__ rp, const int* __restrict__ es,
    const float* __restrict__ dinv, const float* __restrict__ r1p,
    const float* __restrict__ W2, const float* __restrict__ b2,
    float* __restrict__ out) {
    __shared__ float w2[H_MID * C_OUT];   // 640
    __shared__ float a2[16 * 17];         // padded
    int t = threadIdx.x;
    for (int i = t; i < H_MID * C_OUT; i += 256) w2[i] = W2[i];
    int tile = blockIdx.x;
    int node = tile * 16 + (t >> 4), j = t & 15;
    float dv = dinv[node];
    int beg = rp[node], end = rp[node + 1];
    float acc = r1p[(size_t)node * H_MID + j];    // self loop (pre-scaled)
    int e = beg;
    for (; e + 4 <= end; e += 4) {
        int s0 = es[e], s1 = es[e + 1], s2 = es[e + 2], s3 = es[e + 3];
        float v0 = r1p[(size_t)s0 * H_MID + j];
        float v1 = r1p[(size_t)s1 * H_MID + j];
        float v2 = r1p[(size_t)s2 * H_MID + j];
        float v3 = r1p[(size_t)s3 * H_MID + j];
        acc += v0 + v1 + v2 + v3;
    }
    for (; e < end; ++e) acc += r1p[(size_t)es[e] * H_MID + j];
    a2[(t >> 4) * 17 + j] = dv * acc;
    __syncthreads();
    for (int idx = t; idx < 16 * C_OUT; idx += 256) {
        int nd = idx / C_OUT, c = idx % C_OUT;
        float s = b2[c];
#pragma unroll
        for (int jj = 0; jj < H_MID; ++jj) s += a2[nd * 17 + jj] * w2[jj * C_OUT + c];
        out[((size_t)tile * 16 + nd) * C_OUT + c] = s;
    }
}

extern "C" void kernel_launch(void* const* d_in, const int* in_sizes, int n_in,
                              void* d_out, int out_size, void* d_ws, size_t ws_size,
                              hipStream_t stream) {
    const float* x  = (const float*)d_in[0];
    const int*   ei = (const int*)d_in[1];     // [2, E]: row 0 = src, row 1 = dst
    const float* W1 = (const float*)d_in[2];
    const float* b1 = (const float*)d_in[3];
    const float* W2 = (const float*)d_in[4];
    const float* b2 = (const float*)d_in[5];
    float* out = (float*)d_out;

    const int* src = ei;
    const int* dst = ei + N_EDGES;

    // ws layout (4B units):
    //   rp[100352] | part[1024] | dinv[100352] | es[3.2M] | h1p[1.6M] | r1p[1.6M]
    //   ~= 26.4 MiB.
    // d_out (16MB) is free scratch until k_gather2 (sole writer of out):
    //   cnt[100352*CPAD] (1.6MB) | rank[3.2M] (12.8MB)  = 14.4MB <= 16MB.
    int* rp     = (int*)d_ws;
    int* part   = rp + 100352;
    float* dinv = (float*)(part + 1024);
    int* es     = (int*)(dinv + 100352);
    float* h1p  = (float*)(es + N_EDGES);
    float* r1p  = h1p + (size_t)N_NODES * H_MID;
    int* cnt    = (int*)d_out;
    int* rank   = cnt + 100352 * CPAD;

    const int B = 256;
    const int GB = (G_EDGE + B - 1) / B;      // 1563

    k_zero<<<(100352 * CPAD) / B, B, 0, stream>>>(cnt);    // 1568 blocks exact
    k_count_rank<<<GB, B, 0, stream>>>(dst, cnt, rank);
    k_scan1<<<NB, B, 0, stream>>>(cnt, rp, part, dinv);
    k_scan2<<<1, 512, 0, stream>>>(part);
    k_scan3<<<NB, B, 0, stream>>>(rp, part);
    k_gemm1<<<N_NODES / 16, B, 0, stream>>>(x, W1, dinv, h1p);
    k_permute<<<GB, B, 0, stream>>>(src, dst, rank, rp, es);
    k_gather1<<<N_NODES / 16, B, 0, stream>>>(rp, es, dinv, h1p, b1, r1p);
    k_gather2<<<N_NODES / 16, B, 0, stream>>>(rp, es, dinv, r1p, W2, b2, out);
}

// Round 4
// 400.758 us; speedup vs baseline: 1.5179x; 1.0597x over previous
//
#include <hip/hip_runtime.h>

// GCN 2-layer: N=100000, F=128 -> H=16 (relu) -> C=40, E=3200000.
//
// R5: move the histogram+rank atomics from the device-scope coherence point
// into the XCD-local L2.
// Evidence: R4's k_count_rank ran at 23.5 G atomic-txn/s; R0's line-coalesced
// scatter ran at 19 G line-txn/s -- same wall. Device-scope atomics execute
// beyond L2 (per-XCD L2s are non-coherent), and WRITE_SIZE ~= 3.2M x 32B
// shows each atomic is a memory-side sector transaction. ILP can't beat a
// transaction-rate wall.
// Fix: per-XCD histogram replicas. Each block reads its physical XCD id via
// s_getreg(HW_REG_XCC_ID) (HW-verified) and uses WORKGROUP-scope
// __hip_atomic_fetch_add on its own replica: no coherence bits -> the RMW
// executes at the XCD's L2, which is the shared serialization point for every
// CU on that XCD. Correct for any block->XCD assignment (no dispatch-order
// assumption). rank[e] packs (xcd<<27)|local_rank; scan3 builds per-(xcd,node)
// segment bases rp8 so the permute stays one random read per edge.
//
// Math: norm(s->d) = dinv[s]*dinv[d], self-loop norm = dinv[n]^2.
//   h1p = (x@W1)*dinv            (pre-scaled => no dinv[src] gather per edge)
//   agg1[n] = dinv[n]*(h1p[n] + sum_{s in in(n)} h1p[s])
//   r1p[n]  = relu(agg1[n]+b1)*dinv[n]          (fused in gather1 epilogue)
//   agg2[n] = dinv[n]*(r1p[n] + sum r1p[s])
//   out[n]  = agg2[n]@W2 + b2                   (fused in gather2 epilogue)

#define N_NODES     100000
#define NODE_STRIDE 100352        // per-replica stride (ints)
#define F_IN        128
#define H_MID       16
#define C_OUT       40
#define N_EDGES     3200000
#define NB          391           // ceil(N_NODES/256)
#define EPT         8             // edges per thread in edge passes
#define G_EDGE      (N_EDGES / EPT)   // 400000 threads, exact
#define NXCD        8
#define RANK_MASK   0x07FFFFFF

static __device__ __forceinline__ int xcc_id() {
    unsigned x;
    asm volatile("s_getreg_b32 %0, hwreg(HW_REG_XCC_ID)" : "=s"(x));
    return (int)(x & 7u);
}

__global__ void k_zero(int* __restrict__ cnt8) {
    int i = blockIdx.x * 256 + threadIdx.x;   // over NODE_STRIDE*NXCD = 802816 = 3136*256
    cnt8[i] = 0;
}

// Fused histogram + rank into the XCD-local replica. Workgroup-scope atomics
// execute at this XCD's L2 (400KB replica, L2-resident). 8 independent
// return-atomics in flight per thread; rank store is coalesced.
__global__ void __launch_bounds__(256) k_count_rank(
    const int* __restrict__ dst, int* __restrict__ cnt8, int* __restrict__ rank) {
    int tid = blockIdx.x * 256 + threadIdx.x;
    if (tid >= G_EDGE) return;
    int x = xcc_id();
    int* cnt = cnt8 + (size_t)x * NODE_STRIDE;
    int xtag = x << 27;
    int d[EPT], r[EPT];
#pragma unroll
    for (int k = 0; k < EPT; ++k) d[k] = dst[tid + k * G_EDGE];
#pragma unroll
    for (int k = 0; k < EPT; ++k)
        r[k] = __hip_atomic_fetch_add(&cnt[d[k]], 1, __ATOMIC_RELAXED,
                                      __HIP_MEMORY_SCOPE_WORKGROUP);
#pragma unroll
    for (int k = 0; k < EPT; ++k) rank[tid + k * G_EDGE] = xtag | r[k];
}

// block-local exclusive scan of per-node totals -> rp, block sums -> part,
// dinv = rsqrt(1 + total indegree)
__global__ void __launch_bounds__(256) k_scan1(const int* __restrict__ cnt8,
                                               int* __restrict__ rp,
                                               int* __restrict__ part,
                                               float* __restrict__ dinv) {
    __shared__ int s[256];
    int t = threadIdx.x;
    int i = blockIdx.x * 256 + t;
    int v = 0;
    if (i < N_NODES) {
#pragma unroll
        for (int x = 0; x < NXCD; ++x) v += cnt8[x * NODE_STRIDE + i];
    }
    s[t] = v;
    __syncthreads();
    for (int off = 1; off < 256; off <<= 1) {
        int xval = (t >= off) ? s[t - off] : 0;
        __syncthreads();
        s[t] += xval;
        __syncthreads();
    }
    if (i < N_NODES) {
        rp[i] = s[t] - v;                       // exclusive (block-local)
        dinv[i] = rsqrtf(1.0f + (float)v);      // deg = indeg + self loop
    }
    if (t == 255) part[blockIdx.x] = s[255];
}

// exclusive scan of the NB block sums (single block)
__global__ void __launch_bounds__(512) k_scan2(int* __restrict__ part) {
    __shared__ int s[512];
    int t = threadIdx.x;
    int v = (t < NB) ? part[t] : 0;
    s[t] = v;
    __syncthreads();
    for (int off = 1; off < 512; off <<= 1) {
        int x = (t >= off) ? s[t - off] : 0;
        __syncthreads();
        s[t] += x;
        __syncthreads();
    }
    if (t < NB) part[t] = s[t] - v;
}

// finalize rp and build per-(xcd,node) segment bases:
// rp8[x][n] = rp[n] + sum_{y<x} cnt8[y][n]
__global__ void k_scan3(int* __restrict__ rp, const int* __restrict__ part,
                        const int* __restrict__ cnt8, int* __restrict__ rp8) {
    int i = blockIdx.x * 256 + threadIdx.x;
    if (i < N_NODES) {
        int v = rp[i] + part[blockIdx.x];
        rp[i] = v;
        int run = v;
#pragma unroll
        for (int x = 0; x < NXCD; ++x) {
            rp8[x * NODE_STRIDE + i] = run;
            run += cnt8[x * NODE_STRIDE + i];
        }
    }
    if (i == 0) rp[N_NODES] = N_EDGES;
}

// counting-sort edges by dst, atomic-free:
// es[rp8[xcd][d] + local_rank] = src. Only random READ is rp8 (L2-resident).
__global__ void __launch_bounds__(256) k_permute(
    const int* __restrict__ src, const int* __restrict__ dst,
    const int* __restrict__ rank, const int* __restrict__ rp8,
    int* __restrict__ es) {
    int tid = blockIdx.x * 256 + threadIdx.x;
    if (tid >= G_EDGE) return;
    int d[EPT], r[EPT], s[EPT], p[EPT];
#pragma unroll
    for (int k = 0; k < EPT; ++k) d[k] = dst[tid + k * G_EDGE];
#pragma unroll
    for (int k = 0; k < EPT; ++k) r[k] = rank[tid + k * G_EDGE];
#pragma unroll
    for (int k = 0; k < EPT; ++k) s[k] = src[tid + k * G_EDGE];
#pragma unroll
    for (int k = 0; k < EPT; ++k)
        p[k] = rp8[((unsigned)r[k] >> 27) * NODE_STRIDE + d[k]] + (r[k] & RANK_MASK);
#pragma unroll
    for (int k = 0; k < EPT; ++k) es[p[k]] = s[k];
}

// 16 nodes per block, 256 threads = 16 nodes x 16 out-features.
// h1p = (x@W1) * dinv[node]
__global__ void __launch_bounds__(256) k_gemm1(
    const float* __restrict__ x, const float* __restrict__ W1,
    const float* __restrict__ dinv, float* __restrict__ h1p) {
    __shared__ float w[F_IN * H_MID];   // 8 KB
    __shared__ float xs[16 * 132];      // padded rows: no 128-stride conflicts
    int t = threadIdx.x;
    for (int i = t; i < F_IN * H_MID; i += 256) w[i] = W1[i];
    int tile = blockIdx.x;              // 6250 tiles, exact
    const float4* xg = (const float4*)(x + (size_t)tile * 16 * F_IN);
    float4* xs4 = (float4*)xs;          // row stride 33 float4
    for (int i = t; i < 512; i += 256) {
        int r = i >> 5, c4 = i & 31;
        xs4[r * 33 + c4] = xg[r * 32 + c4];
    }
    __syncthreads();
    int node = t >> 4, j = t & 15;
    const float* xr = xs + node * 132;
    float acc = 0.f;
#pragma unroll 8
    for (int k = 0; k < F_IN; ++k) acc += xr[k] * w[k * H_MID + j];
    int g = tile * 16 + node;
    h1p[(size_t)g * H_MID + j] = acc * dinv[g];
}

// gather layer 1 + fused relu/bias/prescale:
// r1p[n] = relu(dinv[n]*(h1p[n] + sum h1p[s]) + b1) * dinv[n]
__global__ void __launch_bounds__(256) k_gather1(
    const int* __restrict__ rp, const int* __restrict__ es,
    const float* __restrict__ dinv, const float* __restrict__ h1p,
    const float* __restrict__ b1, float* __restrict__ r1p) {
    int t = threadIdx.x;
    int node = blockIdx.x * 16 + (t >> 4), j = t & 15;
    float dv = dinv[node];
    int beg = rp[node], end = rp[node + 1];
    float acc = h1p[(size_t)node * H_MID + j];    // self loop (pre-scaled)
    int e = beg;
    for (; e + 4 <= end; e += 4) {
        int s0 = es[e], s1 = es[e + 1], s2 = es[e + 2], s3 = es[e + 3];
        float v0 = h1p[(size_t)s0 * H_MID + j];
        float v1 = h1p[(size_t)s1 * H_MID + j];
        float v2 = h1p[(size_t)s2 * H_MID + j];
        float v3 = h1p[(size_t)s3 * H_MID + j];
        acc += v0 + v1 + v2 + v3;
    }
    for (; e < end; ++e) acc += h1p[(size_t)es[e] * H_MID + j];
    float agg1 = dv * acc;
    r1p[(size_t)node * H_MID + j] = fmaxf(agg1 + b1[j], 0.f) * dv;
}

// gather layer 2 + fused @W2 + b2 epilogue (LDS).
__global__ void __launch_bounds__(256) k_gather2(
    const int* __restrict__ rp, const int* __restrict__ es,
    const float* __restrict__ dinv, const float* __restrict__ r1p,
    const float* __restrict__ W2, const float* __restrict__ b2,
    float* __restrict__ out) {
    __shared__ float w2[H_MID * C_OUT];   // 640
    __shared__ float a2[16 * 17];         // padded
    int t = threadIdx.x;
    for (int i = t; i < H_MID * C_OUT; i += 256) w2[i] = W2[i];
    int tile = blockIdx.x;
    int node = tile * 16 + (t >> 4), j = t & 15;
    float dv = dinv[node];
    int beg = rp[node], end = rp[node + 1];
    float acc = r1p[(size_t)node * H_MID + j];    // self loop (pre-scaled)
    int e = beg;
    for (; e + 4 <= end; e += 4) {
        int s0 = es[e], s1 = es[e + 1], s2 = es[e + 2], s3 = es[e + 3];
        float v0 = r1p[(size_t)s0 * H_MID + j];
        float v1 = r1p[(size_t)s1 * H_MID + j];
        float v2 = r1p[(size_t)s2 * H_MID + j];
        float v3 = r1p[(size_t)s3 * H_MID + j];
        acc += v0 + v1 + v2 + v3;
    }
    for (; e < end; ++e) acc += r1p[(size_t)es[e] * H_MID + j];
    a2[(t >> 4) * 17 + j] = dv * acc;
    __syncthreads();
    for (int idx = t; idx < 16 * C_OUT; idx += 256) {
        int nd = idx / C_OUT, c = idx % C_OUT;
        float s = b2[c];
#pragma unroll
        for (int jj = 0; jj < H_MID; ++jj) s += a2[nd * 17 + jj] * w2[jj * C_OUT + c];
        out[((size_t)tile * 16 + nd) * C_OUT + c] = s;
    }
}

extern "C" void kernel_launch(void* const* d_in, const int* in_sizes, int n_in,
                              void* d_out, int out_size, void* d_ws, size_t ws_size,
                              hipStream_t stream) {
    const float* x  = (const float*)d_in[0];
    const int*   ei = (const int*)d_in[1];     // [2, E]: row 0 = src, row 1 = dst
    const float* W1 = (const float*)d_in[2];
    const float* b1 = (const float*)d_in[3];
    const float* W2 = (const float*)d_in[4];
    const float* b2 = (const float*)d_in[5];
    float* out = (float*)d_out;

    const int* src = ei;
    const int* dst = ei + N_EDGES;

    // ws layout (4B units), unchanged 26.4 MiB:
    //   rp[100352] | part[1024] | dinv[100352] | es[3.2M] | h1p[1.6M] | r1p[1.6M]
    // Aliases (lifetime-disjoint):
    //   cnt8 (8*100352 ints = 3.2MB)  -> es region   (dead before k_permute writes es)
    //   rank (3.2M ints = 12.8MB)     -> h1p+r1p     (dead before k_gemm1 writes h1p)
    //   rp8  (8*100352 ints = 3.2MB)  -> d_out       (dead before k_gather2 writes out)
    int* rp     = (int*)d_ws;
    int* part   = rp + NODE_STRIDE;
    float* dinv = (float*)(part + 1024);
    int* es     = (int*)(dinv + NODE_STRIDE);
    float* h1p  = (float*)(es + N_EDGES);
    float* r1p  = h1p + (size_t)N_NODES * H_MID;
    int* cnt8   = es;
    int* rank   = (int*)h1p;
    int* rp8    = (int*)d_out;

    const int B = 256;
    const int GB = (G_EDGE + B - 1) / B;      // 1563

    k_zero<<<(NODE_STRIDE * NXCD) / B, B, 0, stream>>>(cnt8);   // 3136 exact
    k_count_rank<<<GB, B, 0, stream>>>(dst, cnt8, rank);
    k_scan1<<<NB, B, 0, stream>>>(cnt8, rp, part, dinv);
    k_scan2<<<1, 512, 0, stream>>>(part);
    k_scan3<<<NB, B, 0, stream>>>(rp, part, cnt8, rp8);
    k_permute<<<GB, B, 0, stream>>>(src, dst, rank, rp8, es);
    k_gemm1<<<N_NODES / 16, B, 0, stream>>>(x, W1, dinv, h1p);
    k_gather1<<<N_NODES / 16, B, 0, stream>>>(rp, es, dinv, h1p, b1, r1p);
    k_gather2<<<N_NODES / 16, B, 0, stream>>>(rp, es, dinv, r1p, W2, b2, out);
}

// Round 5
// 288.105 us; speedup vs baseline: 2.1114x; 1.3910x over previous
//
#include <hip/hip_runtime.h>

// GCN 2-layer: N=100000, F=128 -> H=16 (relu) -> C=40, E=3200000.
//
// R6: remove ALL global atomics from the CSR build.
// Evidence chain: R4 (ILP 8x -> only 2.1x) and R5 (workgroup-scope per-XCD
// replicas -> zero change, WRITE_SIZE still 3.2M x 32B) prove random global
// atomics are latency x in-flight-cap bound at ~23G txn/s (256 CU x ~64
// outstanding / ~700ns RTT to the memory-side coherence point). Scope does
// not steer the RMW execution point on gfx950. The only way past the wall is
// to not issue device-scope atomics at all.
// Fix: deterministic radix-partition counting sort, LDS atomics only:
//   k_hist : per-chunk LDS histogram over 782 buckets (128 nodes each)
//            -> hist[bucket][block]  (no atomics to global)
//   scanA/B/C: exclusive scan of hist in bucket-major order -> exact
//            contention-free base offset per (block,bucket)
//   k_part : re-read chunk, LDS return-atomic rank, write packed
//            (loc7|src17) to eb[base+rank]  (contiguous ~10-edge runs)
//   k_csr  : one block per bucket: LDS degree histogram + LDS scan ->
//            rp, dinv; LDS-cursor scatter of src -> node-sorted es
//            (stores confined to the bucket's 16KB window)
// k_gemm1 / k_gather1 / k_gather2 unchanged (proven).
//
// Math: norm(s->d) = dinv[s]*dinv[d], self-loop norm = dinv[n]^2.
//   h1p = (x@W1)*dinv            (pre-scaled => no dinv[src] gather per edge)
//   agg1[n] = dinv[n]*(h1p[n] + sum_{s in in(n)} h1p[s])
//   r1p[n]  = relu(agg1[n]+b1)*dinv[n]          (fused in gather1 epilogue)
//   agg2[n] = dinv[n]*(r1p[n] + sum r1p[s])
//   out[n]  = agg2[n]@W2 + b2                   (fused in gather2 epilogue)

#define N_NODES 100000
#define F_IN    128
#define H_MID   16
#define C_OUT   40
#define N_EDGES 3200000

#define EC      8192                 // edges per chunk (k_hist / k_part block)
#define EBLK    391                  // ceil(N_EDGES / EC)
#define NBUK    782                  // buckets of 128 nodes: covers 0..100095
#define M_HIST  (NBUK * EBLK)        // 305762
#define NPART   598                  // ceil(M_HIST / 512)
#define SRC_MASK 0x1FFFF             // src < 100000 < 2^17

// ---------------- CSR build: radix partition (no global atomics) -----------

__global__ void __launch_bounds__(512) k_hist(
    const int* __restrict__ dst, int* __restrict__ hist) {
    __shared__ int h[NBUK];
    int t = threadIdx.x, blk = blockIdx.x;
    for (int i = t; i < NBUK; i += 512) h[i] = 0;
    __syncthreads();
#pragma unroll
    for (int i = 0; i < EC / 512; ++i) {
        int e = blk * EC + i * 512 + t;
        if (e < N_EDGES) atomicAdd(&h[dst[e] >> 7], 1);   // LDS atomic
    }
    __syncthreads();
    for (int b = t; b < NBUK; b += 512) hist[b * EBLK + blk] = h[b];
}

// block-local exclusive scan over the linear hist array (bucket-major)
__global__ void __launch_bounds__(512) k_scanA(int* __restrict__ hist,
                                               int* __restrict__ part) {
    __shared__ int s[512];
    int t = threadIdx.x;
    int i = blockIdx.x * 512 + t;
    int v = (i < M_HIST) ? hist[i] : 0;
    s[t] = v;
    __syncthreads();
    for (int off = 1; off < 512; off <<= 1) {
        int x = (t >= off) ? s[t - off] : 0;
        __syncthreads();
        s[t] += x;
        __syncthreads();
    }
    if (i < M_HIST) hist[i] = s[t] - v;
    if (t == 511) part[blockIdx.x] = s[511];
}

__global__ void __launch_bounds__(1024) k_scanB(int* __restrict__ part) {
    __shared__ int s[1024];
    int t = threadIdx.x;
    int v = (t < NPART) ? part[t] : 0;
    s[t] = v;
    __syncthreads();
    for (int off = 1; off < 1024; off <<= 1) {
        int x = (t >= off) ? s[t - off] : 0;
        __syncthreads();
        s[t] += x;
        __syncthreads();
    }
    if (t < NPART) part[t] = s[t] - v;
}

__global__ void __launch_bounds__(512) k_scanC(int* __restrict__ hist,
                                               const int* __restrict__ part) {
    int i = blockIdx.x * 512 + threadIdx.x;
    if (i < M_HIST) hist[i] += part[blockIdx.x];
}

// partition edges into buckets: eb[pos] = (loc<<17)|src, pos from LDS cursor
__global__ void __launch_bounds__(512) k_part(
    const int* __restrict__ src, const int* __restrict__ dst,
    const int* __restrict__ hist, int* __restrict__ eb) {
    __shared__ int cur[NBUK];
    int t = threadIdx.x, blk = blockIdx.x;
    for (int b = t; b < NBUK; b += 512) cur[b] = hist[b * EBLK + blk];
    __syncthreads();
#pragma unroll
    for (int i = 0; i < EC / 512; ++i) {
        int e = blk * EC + i * 512 + t;
        if (e < N_EDGES) {
            int d = dst[e], s = src[e];
            int b = d >> 7;
            int pos = atomicAdd(&cur[b], 1);              // LDS return-atomic
            eb[pos] = ((d & 127) << 17) | s;
        }
    }
}

// per-bucket: degree -> rp/dinv; node-sorted scatter of src -> es
__global__ void __launch_bounds__(256) k_csr(
    const int* __restrict__ hist, const int* __restrict__ eb,
    int* __restrict__ rp, float* __restrict__ dinv, int* __restrict__ es) {
    __shared__ int deg[128], scn[128], cur[128];
    int b = blockIdx.x, t = threadIdx.x;
    int bb = hist[b * EBLK];
    int bn = (b + 1 < NBUK) ? hist[(b + 1) * EBLK] : N_EDGES;
    int ecnt = bn - bb;
    if (t < 128) deg[t] = 0;
    __syncthreads();
    for (int i = t; i < ecnt; i += 256) atomicAdd(&deg[eb[bb + i] >> 17], 1);
    __syncthreads();
    if (t < 128) scn[t] = deg[t];
    __syncthreads();
    for (int off = 1; off < 128; off <<= 1) {
        int x = (t < 128 && t >= off) ? scn[t - off] : 0;
        __syncthreads();
        if (t < 128) scn[t] += x;
        __syncthreads();
    }
    if (t < 128) {
        int ex = scn[t] - deg[t];                 // exclusive within bucket
        cur[t] = ex;
        int node = b * 128 + t;                   // < 100096 <= array bounds
        rp[node] = bb + ex;
        dinv[node] = rsqrtf(1.0f + (float)deg[t]);
    }
    __syncthreads();
    for (int i = t; i < ecnt; i += 256) {
        int v = eb[bb + i];
        int r = atomicAdd(&cur[v >> 17], 1);      // LDS return-atomic
        es[bb + r] = v & SRC_MASK;
    }
}

// ---------------- dense kernels (unchanged, proven) ------------------------

// 16 nodes per block, 256 threads = 16 nodes x 16 out-features.
// h1p = (x@W1) * dinv[node]
__global__ void __launch_bounds__(256) k_gemm1(
    const float* __restrict__ x, const float* __restrict__ W1,
    const float* __restrict__ dinv, float* __restrict__ h1p) {
    __shared__ float w[F_IN * H_MID];   // 8 KB
    __shared__ float xs[16 * 132];      // padded rows: no 128-stride conflicts
    int t = threadIdx.x;
    for (int i = t; i < F_IN * H_MID; i += 256) w[i] = W1[i];
    int tile = blockIdx.x;              // 6250 tiles, exact
    const float4* xg = (const float4*)(x + (size_t)tile * 16 * F_IN);
    float4* xs4 = (float4*)xs;          // row stride 33 float4
    for (int i = t; i < 512; i += 256) {
        int r = i >> 5, c4 = i & 31;
        xs4[r * 33 + c4] = xg[r * 32 + c4];
    }
    __syncthreads();
    int node = t >> 4, j = t & 15;
    const float* xr = xs + node * 132;
    float acc = 0.f;
#pragma unroll 8
    for (int k = 0; k < F_IN; ++k) acc += xr[k] * w[k * H_MID + j];
    int g = tile * 16 + node;
    h1p[(size_t)g * H_MID + j] = acc * dinv[g];
}

// gather layer 1 + fused relu/bias/prescale:
// r1p[n] = relu(dinv[n]*(h1p[n] + sum h1p[s]) + b1) * dinv[n]
__global__ void __launch_bounds__(256) k_gather1(
    const int* __restrict__ rp, const int* __restrict__ es,
    const float* __restrict__ dinv, const float* __restrict__ h1p,
    const float* __restrict__ b1, float* __restrict__ r1p) {
    int t = threadIdx.x;
    int node = blockIdx.x * 16 + (t >> 4), j = t & 15;
    float dv = dinv[node];
    int beg = rp[node], end = rp[node + 1];
    float acc = h1p[(size_t)node * H_MID + j];    // self loop (pre-scaled)
    int e = beg;
    for (; e + 4 <= end; e += 4) {
        int s0 = es[e], s1 = es[e + 1], s2 = es[e + 2], s3 = es[e + 3];
        float v0 = h1p[(size_t)s0 * H_MID + j];
        float v1 = h1p[(size_t)s1 * H_MID + j];
        float v2 = h1p[(size_t)s2 * H_MID + j];
        float v3 = h1p[(size_t)s3 * H_MID + j];
        acc += v0 + v1 + v2 + v3;
    }
    for (; e < end; ++e) acc += h1p[(size_t)es[e] * H_MID + j];
    float agg1 = dv * acc;
    r1p[(size_t)node * H_MID + j] = fmaxf(agg1 + b1[j], 0.f) * dv;
}

// gather layer 2 + fused @W2 + b2 epilogue (LDS).
__global__ void __launch_bounds__(256) k_gather2(
    const int* __restrict__ rp, const int* __restrict__ es,
    const float* __restrict__ dinv, const float* __restrict__ r1p,
    const float* __restrict__ W2, const float* __restrict__ b2,
    float* __restrict__ out) {
    __shared__ float w2[H_MID * C_OUT];   // 640
    __shared__ float a2[16 * 17];         // padded
    int t = threadIdx.x;
    for (int i = t; i < H_MID * C_OUT; i += 256) w2[i] = W2[i];
    int tile = blockIdx.x;
    int node = tile * 16 + (t >> 4), j = t & 15;
    float dv = dinv[node];
    int beg = rp[node], end = rp[node + 1];
    float acc = r1p[(size_t)node * H_MID + j];    // self loop (pre-scaled)
    int e = beg;
    for (; e + 4 <= end; e += 4) {
        int s0 = es[e], s1 = es[e + 1], s2 = es[e + 2], s3 = es[e + 3];
        float v0 = r1p[(size_t)s0 * H_MID + j];
        float v1 = r1p[(size_t)s1 * H_MID + j];
        float v2 = r1p[(size_t)s2 * H_MID + j];
        float v3 = r1p[(size_t)s3 * H_MID + j];
        acc += v0 + v1 + v2 + v3;
    }
    for (; e < end; ++e) acc += r1p[(size_t)es[e] * H_MID + j];
    a2[(t >> 4) * 17 + j] = dv * acc;
    __syncthreads();
    for (int idx = t; idx < 16 * C_OUT; idx += 256) {
        int nd = idx / C_OUT, c = idx % C_OUT;
        float s = b2[c];
#pragma unroll
        for (int jj = 0; jj < H_MID; ++jj) s += a2[nd * 17 + jj] * w2[jj * C_OUT + c];
        out[((size_t)tile * 16 + nd) * C_OUT + c] = s;
    }
}

extern "C" void kernel_launch(void* const* d_in, const int* in_sizes, int n_in,
                              void* d_out, int out_size, void* d_ws, size_t ws_size,
                              hipStream_t stream) {
    const float* x  = (const float*)d_in[0];
    const int*   ei = (const int*)d_in[1];     // [2, E]: row 0 = src, row 1 = dst
    const float* W1 = (const float*)d_in[2];
    const float* b1 = (const float*)d_in[3];
    const float* W2 = (const float*)d_in[4];
    const float* b2 = (const float*)d_in[5];
    float* out = (float*)d_out;

    const int* src = ei;
    const int* dst = ei + N_EDGES;

    // ws layout (4B units), 26.4 MiB:
    //   rp[100352] | dinv[100352] | es[3.2M] | h1p[1.6M] | r1p[1.6M]
    // d_out (16MB) is free scratch until k_gather2 (sole writer of out):
    //   eb[3.2M] (12.8MB) | hist[306176] (1.22MB) | partA[1024]  = 14.03MB
    int* rp     = (int*)d_ws;
    float* dinv = (float*)(rp + 100352);
    int* es     = (int*)(dinv + 100352);
    float* h1p  = (float*)(es + N_EDGES);
    float* r1p  = h1p + (size_t)N_NODES * H_MID;

    int* eb    = (int*)d_out;
    int* hist  = eb + N_EDGES;
    int* partA = hist + 306176;

    k_hist <<<EBLK, 512, 0, stream>>>(dst, hist);
    k_scanA<<<NPART, 512, 0, stream>>>(hist, partA);
    k_scanB<<<1, 1024, 0, stream>>>(partA);
    k_scanC<<<NPART, 512, 0, stream>>>(hist, partA);
    k_part <<<EBLK, 512, 0, stream>>>(src, dst, hist, eb);
    k_csr  <<<NBUK, 256, 0, stream>>>(hist, eb, rp, dinv, es);
    k_gemm1<<<N_NODES / 16, 256, 0, stream>>>(x, W1, dinv, h1p);
    k_gather1<<<N_NODES / 16, 256, 0, stream>>>(rp, es, dinv, h1p, b1, r1p);
    k_gather2<<<N_NODES / 16, 256, 0, stream>>>(rp, es, dinv, r1p, W2, b2, out);
}

// Round 6
// 262.068 us; speedup vs baseline: 2.3212x; 1.0994x over previous
//
#include <hip/hip_runtime.h>
#include <hip/hip_fp16.h>

// GCN 2-layer: N=100000, F=128 -> H=16 (relu) -> C=40, E=3200000.
//
// R7 (on top of R6's LDS-radix CSR build, which removed all global atomics):
//  1) fp16 intermediates h1p/r1p: random gather working set 6.4->3.2 MB,
//     now fits each XCD's 4MB L2 -> gather L2-miss traffic collapses.
//     Accumulation stays fp32; fp16 RTE adds ~1e-4 abs error (existing
//     absmax 9.8e-4, stable across reorderings). Gather ILP 4->8.
//  2) occupancy fixes for the CSR build: k_hist/k_part at 1024 threads
//     (6256 waves = 76% cap vs R6's 24%), k_csr at 512 threads.
//     R6 evidence: k_part 59us @ VALUBusy 1.6%, occupancy 24% -- scattered
//     4B stores latency-bound with too few waves.
//
// Math: norm(s->d) = dinv[s]*dinv[d], self-loop norm = dinv[n]^2.
//   h1p = (x@W1)*dinv            (pre-scaled => no dinv[src] gather per edge)
//   agg1[n] = dinv[n]*(h1p[n] + sum_{s in in(n)} h1p[s])
//   r1p[n]  = relu(agg1[n]+b1)*dinv[n]          (fused in gather1 epilogue)
//   agg2[n] = dinv[n]*(r1p[n] + sum r1p[s])
//   out[n]  = agg2[n]@W2 + b2                   (fused in gather2 epilogue)

#define N_NODES 100000
#define F_IN    128
#define H_MID   16
#define C_OUT   40
#define N_EDGES 3200000

#define EC      8192                 // edges per chunk (k_hist / k_part block)
#define EBLK    391                  // ceil(N_EDGES / EC)
#define NBUK    782                  // buckets of 128 nodes: covers 0..100095
#define M_HIST  (NBUK * EBLK)        // 305762
#define NPART   598                  // ceil(M_HIST / 512)
#define SRC_MASK 0x1FFFF             // src < 100000 < 2^17

// ---------------- CSR build: radix partition (no global atomics) -----------

__global__ void __launch_bounds__(1024) k_hist(
    const int* __restrict__ dst, int* __restrict__ hist) {
    __shared__ int h[NBUK];
    int t = threadIdx.x, blk = blockIdx.x;
    for (int i = t; i < NBUK; i += 1024) h[i] = 0;
    __syncthreads();
#pragma unroll
    for (int i = 0; i < EC / 1024; ++i) {
        int e = blk * EC + i * 1024 + t;
        if (e < N_EDGES) atomicAdd(&h[dst[e] >> 7], 1);   // LDS atomic
    }
    __syncthreads();
    for (int b = t; b < NBUK; b += 1024) hist[b * EBLK + blk] = h[b];
}

// block-local exclusive scan over the linear hist array (bucket-major)
__global__ void __launch_bounds__(512) k_scanA(int* __restrict__ hist,
                                               int* __restrict__ part) {
    __shared__ int s[512];
    int t = threadIdx.x;
    int i = blockIdx.x * 512 + t;
    int v = (i < M_HIST) ? hist[i] : 0;
    s[t] = v;
    __syncthreads();
    for (int off = 1; off < 512; off <<= 1) {
        int x = (t >= off) ? s[t - off] : 0;
        __syncthreads();
        s[t] += x;
        __syncthreads();
    }
    if (i < M_HIST) hist[i] = s[t] - v;
    if (t == 511) part[blockIdx.x] = s[511];
}

__global__ void __launch_bounds__(1024) k_scanB(int* __restrict__ part) {
    __shared__ int s[1024];
    int t = threadIdx.x;
    int v = (t < NPART) ? part[t] : 0;
    s[t] = v;
    __syncthreads();
    for (int off = 1; off < 1024; off <<= 1) {
        int x = (t >= off) ? s[t - off] : 0;
        __syncthreads();
        s[t] += x;
        __syncthreads();
    }
    if (t < NPART) part[t] = s[t] - v;
}

__global__ void __launch_bounds__(512) k_scanC(int* __restrict__ hist,
                                               const int* __restrict__ part) {
    int i = blockIdx.x * 512 + threadIdx.x;
    if (i < M_HIST) hist[i] += part[blockIdx.x];
}

// partition edges into buckets: eb[pos] = (loc<<17)|src, pos from LDS cursor
__global__ void __launch_bounds__(1024) k_part(
    const int* __restrict__ src, const int* __restrict__ dst,
    const int* __restrict__ hist, int* __restrict__ eb) {
    __shared__ int cur[NBUK];
    int t = threadIdx.x, blk = blockIdx.x;
    for (int b = t; b < NBUK; b += 1024) cur[b] = hist[b * EBLK + blk];
    __syncthreads();
#pragma unroll
    for (int i = 0; i < EC / 1024; ++i) {
        int e = blk * EC + i * 1024 + t;
        if (e < N_EDGES) {
            int d = dst[e], s = src[e];
            int b = d >> 7;
            int pos = atomicAdd(&cur[b], 1);              // LDS return-atomic
            eb[pos] = ((d & 127) << 17) | s;
        }
    }
}

// per-bucket: degree -> rp/dinv; node-sorted scatter of src -> es
__global__ void __launch_bounds__(512) k_csr(
    const int* __restrict__ hist, const int* __restrict__ eb,
    int* __restrict__ rp, float* __restrict__ dinv, int* __restrict__ es) {
    __shared__ int deg[128], scn[128], cur[128];
    int b = blockIdx.x, t = threadIdx.x;
    int bb = hist[b * EBLK];
    int bn = (b + 1 < NBUK) ? hist[(b + 1) * EBLK] : N_EDGES;
    int ecnt = bn - bb;
    if (t < 128) deg[t] = 0;
    __syncthreads();
    for (int i = t; i < ecnt; i += 512) atomicAdd(&deg[eb[bb + i] >> 17], 1);
    __syncthreads();
    if (t < 128) scn[t] = deg[t];
    __syncthreads();
    for (int off = 1; off < 128; off <<= 1) {
        int x = (t < 128 && t >= off) ? scn[t - off] : 0;
        __syncthreads();
        if (t < 128) scn[t] += x;
        __syncthreads();
    }
    if (t < 128) {
        int ex = scn[t] - deg[t];                 // exclusive within bucket
        cur[t] = ex;
        int node = b * 128 + t;                   // < 100096 <= array bounds
        rp[node] = bb + ex;
        dinv[node] = rsqrtf(1.0f + (float)deg[t]);
    }
    __syncthreads();
    for (int i = t; i < ecnt; i += 512) {
        int v = eb[bb + i];
        int r = atomicAdd(&cur[v >> 17], 1);      // LDS return-atomic
        es[bb + r] = v & SRC_MASK;
    }
}

// ---------------- dense kernels ------------------------

// 16 nodes per block, 256 threads = 16 nodes x 16 out-features.
// h1p = fp16( (x@W1) * dinv[node] )
__global__ void __launch_bounds__(256) k_gemm1(
    const float* __restrict__ x, const float* __restrict__ W1,
    const float* __restrict__ dinv, __half* __restrict__ h1p) {
    __shared__ float w[F_IN * H_MID];   // 8 KB
    __shared__ float xs[16 * 132];      // padded rows: no 128-stride conflicts
    int t = threadIdx.x;
    for (int i = t; i < F_IN * H_MID; i += 256) w[i] = W1[i];
    int tile = blockIdx.x;              // 6250 tiles, exact
    const float4* xg = (const float4*)(x + (size_t)tile * 16 * F_IN);
    float4* xs4 = (float4*)xs;          // row stride 33 float4
    for (int i = t; i < 512; i += 256) {
        int r = i >> 5, c4 = i & 31;
        xs4[r * 33 + c4] = xg[r * 32 + c4];
    }
    __syncthreads();
    int node = t >> 4, j = t & 15;
    const float* xr = xs + node * 132;
    float acc = 0.f;
#pragma unroll 8
    for (int k = 0; k < F_IN; ++k) acc += xr[k] * w[k * H_MID + j];
    int g = tile * 16 + node;
    h1p[(size_t)g * H_MID + j] = __float2half(acc * dinv[g]);
}

// gather layer 1 + fused relu/bias/prescale (fp16 in, fp32 accum, fp16 out):
// r1p[n] = fp16( relu(dinv[n]*(h1p[n] + sum h1p[s]) + b1) * dinv[n] )
__global__ void __launch_bounds__(256) k_gather1(
    const int* __restrict__ rp, const int* __restrict__ es,
    const float* __restrict__ dinv, const __half* __restrict__ h1p,
    const float* __restrict__ b1, __half* __restrict__ r1p) {
    int t = threadIdx.x;
    int node = blockIdx.x * 16 + (t >> 4), j = t & 15;
    float dv = dinv[node];
    int beg = rp[node], end = rp[node + 1];
    float acc = __half2float(h1p[(size_t)node * H_MID + j]);  // self loop
    int e = beg;
    for (; e + 8 <= end; e += 8) {
        int s0 = es[e],     s1 = es[e + 1], s2 = es[e + 2], s3 = es[e + 3];
        int s4 = es[e + 4], s5 = es[e + 5], s6 = es[e + 6], s7 = es[e + 7];
        __half v0 = h1p[(size_t)s0 * H_MID + j];
        __half v1 = h1p[(size_t)s1 * H_MID + j];
        __half v2 = h1p[(size_t)s2 * H_MID + j];
        __half v3 = h1p[(size_t)s3 * H_MID + j];
        __half v4 = h1p[(size_t)s4 * H_MID + j];
        __half v5 = h1p[(size_t)s5 * H_MID + j];
        __half v6 = h1p[(size_t)s6 * H_MID + j];
        __half v7 = h1p[(size_t)s7 * H_MID + j];
        acc += __half2float(v0) + __half2float(v1) + __half2float(v2) + __half2float(v3)
             + __half2float(v4) + __half2float(v5) + __half2float(v6) + __half2float(v7);
    }
    for (; e < end; ++e) acc += __half2float(h1p[(size_t)es[e] * H_MID + j]);
    float agg1 = dv * acc;
    r1p[(size_t)node * H_MID + j] = __float2half(fmaxf(agg1 + b1[j], 0.f) * dv);
}

// gather layer 2 + fused @W2 + b2 epilogue (LDS).
__global__ void __launch_bounds__(256) k_gather2(
    const int* __restrict__ rp, const int* __restrict__ es,
    const float* __restrict__ dinv, const __half* __restrict__ r1p,
    const float* __restrict__ W2, const float* __restrict__ b2,
    float* __restrict__ out) {
    __shared__ float w2[H_MID * C_OUT];   // 640
    __shared__ float a2[16 * 17];         // padded
    int t = threadIdx.x;
    for (int i = t; i < H_MID * C_OUT; i += 256) w2[i] = W2[i];
    int tile = blockIdx.x;
    int node = tile * 16 + (t >> 4), j = t & 15;
    float dv = dinv[node];
    int beg = rp[node], end = rp[node + 1];
    float acc = __half2float(r1p[(size_t)node * H_MID + j]);  // self loop
    int e = beg;
    for (; e + 8 <= end; e += 8) {
        int s0 = es[e],     s1 = es[e + 1], s2 = es[e + 2], s3 = es[e + 3];
        int s4 = es[e + 4], s5 = es[e + 5], s6 = es[e + 6], s7 = es[e + 7];
        __half v0 = r1p[(size_t)s0 * H_MID + j];
        __half v1 = r1p[(size_t)s1 * H_MID + j];
        __half v2 = r1p[(size_t)s2 * H_MID + j];
        __half v3 = r1p[(size_t)s3 * H_MID + j];
        __half v4 = r1p[(size_t)s4 * H_MID + j];
        __half v5 = r1p[(size_t)s5 * H_MID + j];
        __half v6 = r1p[(size_t)s6 * H_MID + j];
        __half v7 = r1p[(size_t)s7 * H_MID + j];
        acc += __half2float(v0) + __half2float(v1) + __half2float(v2) + __half2float(v3)
             + __half2float(v4) + __half2float(v5) + __half2float(v6) + __half2float(v7);
    }
    for (; e < end; ++e) acc += __half2float(r1p[(size_t)es[e] * H_MID + j]);
    a2[(t >> 4) * 17 + j] = dv * acc;
    __syncthreads();
    for (int idx = t; idx < 16 * C_OUT; idx += 256) {
        int nd = idx / C_OUT, c = idx % C_OUT;
        float s = b2[c];
#pragma unroll
        for (int jj = 0; jj < H_MID; ++jj) s += a2[nd * 17 + jj] * w2[jj * C_OUT + c];
        out[((size_t)tile * 16 + nd) * C_OUT + c] = s;
    }
}

extern "C" void kernel_launch(void* const* d_in, const int* in_sizes, int n_in,
                              void* d_out, int out_size, void* d_ws, size_t ws_size,
                              hipStream_t stream) {
    const float* x  = (const float*)d_in[0];
    const int*   ei = (const int*)d_in[1];     // [2, E]: row 0 = src, row 1 = dst
    const float* W1 = (const float*)d_in[2];
    const float* b1 = (const float*)d_in[3];
    const float* W2 = (const float*)d_in[4];
    const float* b2 = (const float*)d_in[5];
    float* out = (float*)d_out;

    const int* src = ei;
    const int* dst = ei + N_EDGES;

    // ws layout (4B units), ~20 MiB:
    //   rp[100352] | dinv[100352] | es[3.2M] | h1p[1.6M __half = 3.2MB] |
    //   r1p[1.6M __half = 3.2MB]
    // d_out (16MB) is free scratch until k_gather2 (sole writer of out):
    //   eb[3.2M] (12.8MB) | hist[306176] (1.22MB) | partA[1024]  = 14.03MB
    int* rp     = (int*)d_ws;
    float* dinv = (float*)(rp + 100352);
    int* es     = (int*)(dinv + 100352);
    __half* h1p = (__half*)(es + N_EDGES);
    __half* r1p = h1p + (size_t)N_NODES * H_MID;

    int* eb    = (int*)d_out;
    int* hist  = eb + N_EDGES;
    int* partA = hist + 306176;

    k_hist <<<EBLK, 1024, 0, stream>>>(dst, hist);
    k_scanA<<<NPART, 512, 0, stream>>>(hist, partA);
    k_scanB<<<1, 1024, 0, stream>>>(partA);
    k_scanC<<<NPART, 512, 0, stream>>>(hist, partA);
    k_part <<<EBLK, 1024, 0, stream>>>(src, dst, hist, eb);
    k_csr  <<<NBUK, 512, 0, stream>>>(hist, eb, rp, dinv, es);
    k_gemm1<<<N_NODES / 16, 256, 0, stream>>>(x, W1, dinv, h1p);
    k_gather1<<<N_NODES / 16, 256, 0, stream>>>(rp, es, dinv, h1p, b1, r1p);
    k_gather2<<<N_NODES / 16, 256, 0, stream>>>(rp, es, dinv, r1p, W2, b2, out);
}

// Round 7
// 241.499 us; speedup vs baseline: 2.5189x; 1.0852x over previous
//
#include <hip/hip_runtime.h>
#include <hip/hip_fp16.h>

// GCN 2-layer: N=100000, F=128 -> H=16 (relu) -> C=40, E=3200000.
//
// R8 (on R7's fp16-intermediate + LDS-radix pipeline):
// k_part write-combining fix. R7 evidence: k_part WRITE_SIZE 55MB for a
// 12.8MB output (4.3x amplification), VALUBusy 2% -- scattered 4B stores
// into 782 runs/block = ~200KB live window/block x 64 resident blocks/XCD
// = 13MB >> 4MB L2 -> partial-line evictions (HBM RMW).
// Fix: buckets 128 -> 256 nodes (NBUK 782 -> 391): runs ~21 edges, window
// ~58KB/block x 64 = 3.7MB <= L2 -> lines written back once, full.
// Also: k_scanC fused into k_part/k_csr cursor loads (one less pass);
// k_csr now covers node 100000 naturally (no rp[N] special case).
//
// Math: norm(s->d) = dinv[s]*dinv[d], self-loop norm = dinv[n]^2.
//   h1p = (x@W1)*dinv            (pre-scaled => no dinv[src] gather per edge)
//   agg1[n] = dinv[n]*(h1p[n] + sum_{s in in(n)} h1p[s])
//   r1p[n]  = relu(agg1[n]+b1)*dinv[n]          (fused in gather1 epilogue)
//   agg2[n] = dinv[n]*(r1p[n] + sum r1p[s])
//   out[n]  = agg2[n]@W2 + b2                   (fused in gather2 epilogue)

#define N_NODES 100000
#define F_IN    128
#define H_MID   16
#define C_OUT   40
#define N_EDGES 3200000

#define EC      8192                 // edges per chunk (k_hist / k_part block)
#define EBLK    391                  // ceil(N_EDGES / EC)
#define NBUK    391                  // buckets of 256 nodes: covers 0..100095
#define M_HIST  (NBUK * EBLK)        // 152881
#define NPART   299                  // ceil(M_HIST / 512)
#define SRC_MASK 0x1FFFF             // src < 100000 < 2^17

// ---------------- CSR build: radix partition (no global atomics) -----------

__global__ void __launch_bounds__(1024) k_hist(
    const int* __restrict__ dst, int* __restrict__ hist) {
    __shared__ int h[NBUK];
    int t = threadIdx.x, blk = blockIdx.x;
    for (int i = t; i < NBUK; i += 1024) h[i] = 0;
    __syncthreads();
#pragma unroll
    for (int i = 0; i < EC / 1024; ++i) {
        int e = blk * EC + i * 1024 + t;
        if (e < N_EDGES) atomicAdd(&h[dst[e] >> 8], 1);   // LDS atomic
    }
    __syncthreads();
    for (int b = t; b < NBUK; b += 1024) hist[b * EBLK + blk] = h[b];
}

// block-local exclusive scan over the linear hist array (bucket-major)
__global__ void __launch_bounds__(512) k_scanA(int* __restrict__ hist,
                                               int* __restrict__ part) {
    __shared__ int s[512];
    int t = threadIdx.x;
    int i = blockIdx.x * 512 + t;
    int v = (i < M_HIST) ? hist[i] : 0;
    s[t] = v;
    __syncthreads();
    for (int off = 1; off < 512; off <<= 1) {
        int x = (t >= off) ? s[t - off] : 0;
        __syncthreads();
        s[t] += x;
        __syncthreads();
    }
    if (i < M_HIST) hist[i] = s[t] - v;
    if (t == 511) part[blockIdx.x] = s[511];
}

// exclusive scan of the NPART block sums (single block); hist stays
// block-local-exclusive -- consumers add part[idx>>9] on the fly.
__global__ void __launch_bounds__(512) k_scanB(int* __restrict__ part) {
    __shared__ int s[512];
    int t = threadIdx.x;
    int v = (t < NPART) ? part[t] : 0;
    s[t] = v;
    __syncthreads();
    for (int off = 1; off < 512; off <<= 1) {
        int x = (t >= off) ? s[t - off] : 0;
        __syncthreads();
        s[t] += x;
        __syncthreads();
    }
    if (t < NPART) part[t] = s[t] - v;
}

// partition edges into buckets: eb[pos] = (loc8<<17)|src17, pos from LDS cursor
__global__ void __launch_bounds__(1024) k_part(
    const int* __restrict__ src, const int* __restrict__ dst,
    const int* __restrict__ hist, const int* __restrict__ part,
    int* __restrict__ eb) {
    __shared__ int cur[NBUK];
    int t = threadIdx.x, blk = blockIdx.x;
    for (int b = t; b < NBUK; b += 1024) {
        int idx = b * EBLK + blk;
        cur[b] = hist[idx] + part[idx >> 9];      // fused scanC
    }
    __syncthreads();
#pragma unroll
    for (int i = 0; i < EC / 1024; ++i) {
        int e = blk * EC + i * 1024 + t;
        if (e < N_EDGES) {
            int d = dst[e], s = src[e];
            int b = d >> 8;
            int pos = atomicAdd(&cur[b], 1);              // LDS return-atomic
            eb[pos] = ((d & 255) << 17) | s;
        }
    }
}

// per-bucket (256 nodes): degree -> rp/dinv; node-sorted scatter of src -> es
__global__ void __launch_bounds__(512) k_csr(
    const int* __restrict__ hist, const int* __restrict__ part,
    const int* __restrict__ eb,
    int* __restrict__ rp, float* __restrict__ dinv, int* __restrict__ es) {
    __shared__ int deg[256], scn[256], cur[256];
    int b = blockIdx.x, t = threadIdx.x;
    int i0 = b * EBLK;
    int bb = hist[i0] + part[i0 >> 9];
    int bn = (b + 1 < NBUK) ? (hist[i0 + EBLK] + part[(i0 + EBLK) >> 9]) : N_EDGES;
    int ecnt = bn - bb;
    if (t < 256) deg[t] = 0;
    __syncthreads();
    for (int i = t; i < ecnt; i += 512) atomicAdd(&deg[eb[bb + i] >> 17], 1);
    __syncthreads();
    if (t < 256) scn[t] = deg[t];
    __syncthreads();
    for (int off = 1; off < 256; off <<= 1) {
        int x = (t < 256 && t >= off) ? scn[t - off] : 0;
        __syncthreads();
        if (t < 256) scn[t] += x;
        __syncthreads();
    }
    if (t < 256) {
        int ex = scn[t] - deg[t];                 // exclusive within bucket
        cur[t] = ex;
        int node = b * 256 + t;                   // < 100096 <= array bounds
        rp[node] = bb + ex;                       // rp[100000] == N_EDGES naturally
        dinv[node] = rsqrtf(1.0f + (float)deg[t]);
    }
    __syncthreads();
    for (int i = t; i < ecnt; i += 512) {
        int v = eb[bb + i];
        int r = atomicAdd(&cur[v >> 17], 1);      // LDS return-atomic
        es[bb + r] = v & SRC_MASK;
    }
}

// ---------------- dense kernels (unchanged, proven) ------------------------

// 16 nodes per block, 256 threads = 16 nodes x 16 out-features.
// h1p = fp16( (x@W1) * dinv[node] )
__global__ void __launch_bounds__(256) k_gemm1(
    const float* __restrict__ x, const float* __restrict__ W1,
    const float* __restrict__ dinv, __half* __restrict__ h1p) {
    __shared__ float w[F_IN * H_MID];   // 8 KB
    __shared__ float xs[16 * 132];      // padded rows: no 128-stride conflicts
    int t = threadIdx.x;
    for (int i = t; i < F_IN * H_MID; i += 256) w[i] = W1[i];
    int tile = blockIdx.x;              // 6250 tiles, exact
    const float4* xg = (const float4*)(x + (size_t)tile * 16 * F_IN);
    float4* xs4 = (float4*)xs;          // row stride 33 float4
    for (int i = t; i < 512; i += 256) {
        int r = i >> 5, c4 = i & 31;
        xs4[r * 33 + c4] = xg[r * 32 + c4];
    }
    __syncthreads();
    int node = t >> 4, j = t & 15;
    const float* xr = xs + node * 132;
    float acc = 0.f;
#pragma unroll 8
    for (int k = 0; k < F_IN; ++k) acc += xr[k] * w[k * H_MID + j];
    int g = tile * 16 + node;
    h1p[(size_t)g * H_MID + j] = __float2half(acc * dinv[g]);
}

// gather layer 1 + fused relu/bias/prescale (fp16 in, fp32 accum, fp16 out):
// r1p[n] = fp16( relu(dinv[n]*(h1p[n] + sum h1p[s]) + b1) * dinv[n] )
__global__ void __launch_bounds__(256) k_gather1(
    const int* __restrict__ rp, const int* __restrict__ es,
    const float* __restrict__ dinv, const __half* __restrict__ h1p,
    const float* __restrict__ b1, __half* __restrict__ r1p) {
    int t = threadIdx.x;
    int node = blockIdx.x * 16 + (t >> 4), j = t & 15;
    float dv = dinv[node];
    int beg = rp[node], end = rp[node + 1];
    float acc = __half2float(h1p[(size_t)node * H_MID + j]);  // self loop
    int e = beg;
    for (; e + 8 <= end; e += 8) {
        int s0 = es[e],     s1 = es[e + 1], s2 = es[e + 2], s3 = es[e + 3];
        int s4 = es[e + 4], s5 = es[e + 5], s6 = es[e + 6], s7 = es[e + 7];
        __half v0 = h1p[(size_t)s0 * H_MID + j];
        __half v1 = h1p[(size_t)s1 * H_MID + j];
        __half v2 = h1p[(size_t)s2 * H_MID + j];
        __half v3 = h1p[(size_t)s3 * H_MID + j];
        __half v4 = h1p[(size_t)s4 * H_MID + j];
        __half v5 = h1p[(size_t)s5 * H_MID + j];
        __half v6 = h1p[(size_t)s6 * H_MID + j];
        __half v7 = h1p[(size_t)s7 * H_MID + j];
        acc += __half2float(v0) + __half2float(v1) + __half2float(v2) + __half2float(v3)
             + __half2float(v4) + __half2float(v5) + __half2float(v6) + __half2float(v7);
    }
    for (; e < end; ++e) acc += __half2float(h1p[(size_t)es[e] * H_MID + j]);
    float agg1 = dv * acc;
    r1p[(size_t)node * H_MID + j] = __float2half(fmaxf(agg1 + b1[j], 0.f) * dv);
}

// gather layer 2 + fused @W2 + b2 epilogue (LDS).
__global__ void __launch_bounds__(256) k_gather2(
    const int* __restrict__ rp, const int* __restrict__ es,
    const float* __restrict__ dinv, const __half* __restrict__ r1p,
    const float* __restrict__ W2, const float* __restrict__ b2,
    float* __restrict__ out) {
    __shared__ float w2[H_MID * C_OUT];   // 640
    __shared__ float a2[16 * 17];         // padded
    int t = threadIdx.x;
    for (int i = t; i < H_MID * C_OUT; i += 256) w2[i] = W2[i];
    int tile = blockIdx.x;
    int node = tile * 16 + (t >> 4), j = t & 15;
    float dv = dinv[node];
    int beg = rp[node], end = rp[node + 1];
    float acc = __half2float(r1p[(size_t)node * H_MID + j]);  // self loop
    int e = beg;
    for (; e + 8 <= end; e += 8) {
        int s0 = es[e],     s1 = es[e + 1], s2 = es[e + 2], s3 = es[e + 3];
        int s4 = es[e + 4], s5 = es[e + 5], s6 = es[e + 6], s7 = es[e + 7];
        __half v0 = r1p[(size_t)s0 * H_MID + j];
        __half v1 = r1p[(size_t)s1 * H_MID + j];
        __half v2 = r1p[(size_t)s2 * H_MID + j];
        __half v3 = r1p[(size_t)s3 * H_MID + j];
        __half v4 = r1p[(size_t)s4 * H_MID + j];
        __half v5 = r1p[(size_t)s5 * H_MID + j];
        __half v6 = r1p[(size_t)s6 * H_MID + j];
        __half v7 = r1p[(size_t)s7 * H_MID + j];
        acc += __half2float(v0) + __half2float(v1) + __half2float(v2) + __half2float(v3)
             + __half2float(v4) + __half2float(v5) + __half2float(v6) + __half2float(v7);
    }
    for (; e < end; ++e) acc += __half2float(r1p[(size_t)es[e] * H_MID + j]);
    a2[(t >> 4) * 17 + j] = dv * acc;
    __syncthreads();
    for (int idx = t; idx < 16 * C_OUT; idx += 256) {
        int nd = idx / C_OUT, c = idx % C_OUT;
        float s = b2[c];
#pragma unroll
        for (int jj = 0; jj < H_MID; ++jj) s += a2[nd * 17 + jj] * w2[jj * C_OUT + c];
        out[((size_t)tile * 16 + nd) * C_OUT + c] = s;
    }
}

extern "C" void kernel_launch(void* const* d_in, const int* in_sizes, int n_in,
                              void* d_out, int out_size, void* d_ws, size_t ws_size,
                              hipStream_t stream) {
    const float* x  = (const float*)d_in[0];
    const int*   ei = (const int*)d_in[1];     // [2, E]: row 0 = src, row 1 = dst
    const float* W1 = (const float*)d_in[2];
    const float* b1 = (const float*)d_in[3];
    const float* W2 = (const float*)d_in[4];
    const float* b2 = (const float*)d_in[5];
    float* out = (float*)d_out;

    const int* src = ei;
    const int* dst = ei + N_EDGES;

    // ws layout (4B units), ~20 MiB:
    //   rp[100352] | dinv[100352] | es[3.2M] | h1p[1.6M __half] | r1p[1.6M __half]
    // d_out (16MB) is free scratch until k_gather2 (sole writer of out):
    //   eb[3.2M] (12.8MB) | hist[153088] (0.61MB) | part[512]  ~= 13.4MB
    int* rp     = (int*)d_ws;
    float* dinv = (float*)(rp + 100352);
    int* es     = (int*)(dinv + 100352);
    __half* h1p = (__half*)(es + N_EDGES);
    __half* r1p = h1p + (size_t)N_NODES * H_MID;

    int* eb   = (int*)d_out;
    int* hist = eb + N_EDGES;
    int* part = hist + 153088;

    k_hist <<<EBLK, 1024, 0, stream>>>(dst, hist);
    k_scanA<<<NPART, 512, 0, stream>>>(hist, part);
    k_scanB<<<1, 512, 0, stream>>>(part);
    k_part <<<EBLK, 1024, 0, stream>>>(src, dst, hist, part, eb);
    k_csr  <<<NBUK, 512, 0, stream>>>(hist, part, eb, rp, dinv, es);
    k_gemm1<<<N_NODES / 16, 256, 0, stream>>>(x, W1, dinv, h1p);
    k_gather1<<<N_NODES / 16, 256, 0, stream>>>(rp, es, dinv, h1p, b1, r1p);
    k_gather2<<<N_NODES / 16, 256, 0, stream>>>(rp, es, dinv, r1p, W2, b2, out);
}

// Round 8
// 235.262 us; speedup vs baseline: 2.5857x; 1.0265x over previous
//
#include <hip/hip_runtime.h>
#include <hip/hip_fp16.h>

// GCN 2-layer: N=100000, F=128 -> H=16 (relu) -> C=40, E=3200000.
//
// R9: the pipeline is bound by RANDOM L2 TRANSACTIONS (~4 txn/cy/XCD):
// k_part 43us, k_csr ~40us, gather1/2 ~41us each all sit at the
// 3.2M-txn / (8 XCD x 4/cy x 2.4GHz) = 41.7us floor. Gathers' random row
// reads are algorithmically forced; the CSR build's random STORES are not:
//  - k_part v2: block-local LDS counting sort (hist -> scan -> rank) then
//    COALESCED drain (consecutive lanes -> consecutive positions within
//    each ~21-edge run). Store txns 3.2M -> ~0.4M.
//  - k_csr v2: build the bucket's node-sorted es segment in an LDS buffer
//    (CAP 10240, +5-sigma headroom, direct-scatter fallback), drain
//    coalesced. Store txns 3.2M -> ~0.2M.
//  - nontemporal loads on single-use streams (dst/src/eb/x) to protect the
//    L2 write-combine windows and hot h1p/r1p; nt stores for r1p/out/es.
// Gathers unchanged (at the txn floor; proven kernels).
//
// Math: norm(s->d) = dinv[s]*dinv[d], self-loop norm = dinv[n]^2.
//   h1p = (x@W1)*dinv            (pre-scaled => no dinv[src] gather per edge)
//   agg1[n] = dinv[n]*(h1p[n] + sum_{s in in(n)} h1p[s])
//   r1p[n]  = relu(agg1[n]+b1)*dinv[n]          (fused in gather1 epilogue)
//   agg2[n] = dinv[n]*(r1p[n] + sum r1p[s])
//   out[n]  = agg2[n]@W2 + b2                   (fused in gather2 epilogue)

#define N_NODES 100000
#define F_IN    128
#define H_MID   16
#define C_OUT   40
#define N_EDGES 3200000

#define EC      8192                 // edges per chunk (k_hist / k_part block)
#define EBLK    391                  // ceil(N_EDGES / EC)
#define NBUK    391                  // buckets of 256 nodes: covers 0..100095
#define M_HIST  (NBUK * EBLK)        // 152881
#define NPART   299                  // ceil(M_HIST / 512)
#define SRC_MASK 0x1FFFF             // src < 100000 < 2^17
#define CAP_CSR 10240                // LDS es buffer (mean 8192, sigma~90)

// ---------------- CSR build: radix partition (no global atomics) -----------

__global__ void __launch_bounds__(1024) k_hist(
    const int* __restrict__ dst, int* __restrict__ hist) {
    __shared__ int h[NBUK];
    int t = threadIdx.x, blk = blockIdx.x;
    for (int i = t; i < NBUK; i += 1024) h[i] = 0;
    __syncthreads();
#pragma unroll
    for (int i = 0; i < EC / 1024; ++i) {
        int e = blk * EC + i * 1024 + t;
        if (e < N_EDGES) atomicAdd(&h[__builtin_nontemporal_load(dst + e) >> 8], 1);
    }
    __syncthreads();
    for (int b = t; b < NBUK; b += 1024) hist[b * EBLK + blk] = h[b];
}

// block-local exclusive scan over the linear hist array (bucket-major)
__global__ void __launch_bounds__(512) k_scanA(int* __restrict__ hist,
                                               int* __restrict__ part) {
    __shared__ int s[512];
    int t = threadIdx.x;
    int i = blockIdx.x * 512 + t;
    int v = (i < M_HIST) ? hist[i] : 0;
    s[t] = v;
    __syncthreads();
    for (int off = 1; off < 512; off <<= 1) {
        int x = (t >= off) ? s[t - off] : 0;
        __syncthreads();
        s[t] += x;
        __syncthreads();
    }
    if (i < M_HIST) hist[i] = s[t] - v;
    if (t == 511) part[blockIdx.x] = s[511];
}

// exclusive scan of the NPART block sums (single block); hist stays
// block-local-exclusive -- consumers add part[idx>>9] on the fly.
__global__ void __launch_bounds__(512) k_scanB(int* __restrict__ part) {
    __shared__ int s[512];
    int t = threadIdx.x;
    int v = (t < NPART) ? part[t] : 0;
    s[t] = v;
    __syncthreads();
    for (int off = 1; off < 512; off <<= 1) {
        int x = (t >= off) ? s[t - off] : 0;
        __syncthreads();
        s[t] += x;
        __syncthreads();
    }
    if (t < NPART) part[t] = s[t] - v;
}

// partition edges into buckets via block-local LDS counting sort, then
// coalesced drain: eb[pos] = (loc8<<17)|src17.
__global__ void __launch_bounds__(1024) k_part(
    const int* __restrict__ src, const int* __restrict__ dst,
    const int* __restrict__ hist, const int* __restrict__ part,
    int* __restrict__ eb) {
    __shared__ int cnt[NBUK];
    __shared__ int scn[512];
    __shared__ int dlt[NBUK];
    __shared__ int cr[NBUK];
    __shared__ int sval[EC];
    __shared__ int spos[EC];
    int t = threadIdx.x, blk = blockIdx.x;
    for (int b = t; b < NBUK; b += 1024) cnt[b] = 0;
    __syncthreads();
    int e0 = blk * EC;
    int d[8], s[8], bk[8];
    bool val[8];
#pragma unroll
    for (int k = 0; k < 8; ++k) {
        int e = e0 + k * 1024 + t;
        val[k] = (e < N_EDGES);
        d[k] = val[k] ? __builtin_nontemporal_load(dst + e) : 0;
        s[k] = val[k] ? __builtin_nontemporal_load(src + e) : 0;
        bk[k] = d[k] >> 8;
    }
#pragma unroll
    for (int k = 0; k < 8; ++k)
        if (val[k]) atomicAdd(&cnt[bk[k]], 1);
    __syncthreads();
    // exclusive scan of cnt -> local bases (Hillis-Steele over 512 slots)
    if (t < 512) scn[t] = (t < NBUK) ? cnt[t] : 0;
    __syncthreads();
    for (int off = 1; off < 512; off <<= 1) {
        int x = 0;
        if (t < 512 && t >= off) x = scn[t - off];
        __syncthreads();
        if (t < 512) scn[t] += x;
        __syncthreads();
    }
    for (int b = t; b < NBUK; b += 1024) {
        int idx = b * EBLK + blk;
        int gb = hist[idx] + part[idx >> 9];   // global base of (b, blk) run
        int lb = scn[b] - cnt[b];              // local base (exclusive)
        dlt[b] = gb - lb;
        cr[b] = lb;
    }
    __syncthreads();
#pragma unroll
    for (int k = 0; k < 8; ++k) {
        if (val[k]) {
            int lr = atomicAdd(&cr[bk[k]], 1);           // LDS return-atomic
            sval[lr] = ((d[k] & 255) << 17) | s[k];
            spos[lr] = lr + dlt[bk[k]];
        }
    }
    __syncthreads();
    int n = (e0 + EC <= N_EDGES) ? EC : (N_EDGES - e0);
    for (int i = t; i < n; i += 1024)
        eb[spos[i]] = sval[i];                 // coalesced within ~21-edge runs
}

// per-bucket (256 nodes): degree -> rp/dinv; node-sorted es built in LDS,
// drained coalesced.
__global__ void __launch_bounds__(512) k_csr(
    const int* __restrict__ hist, const int* __restrict__ part,
    const int* __restrict__ eb,
    int* __restrict__ rp, float* __restrict__ dinv, int* __restrict__ es) {
    __shared__ int deg[256], scn[256], cw[256];
    __shared__ int esl[CAP_CSR];
    int b = blockIdx.x, t = threadIdx.x;
    int i0 = b * EBLK;
    int bb = hist[i0] + part[i0 >> 9];
    int bn = (b + 1 < NBUK) ? (hist[i0 + EBLK] + part[(i0 + EBLK) >> 9]) : N_EDGES;
    int ecnt = bn - bb;
    if (t < 256) deg[t] = 0;
    __syncthreads();
    for (int i = t; i < ecnt; i += 512)
        atomicAdd(&deg[__builtin_nontemporal_load(eb + bb + i) >> 17], 1);
    __syncthreads();
    if (t < 256) scn[t] = deg[t];
    __syncthreads();
    for (int off = 1; off < 256; off <<= 1) {
        int x = (t < 256 && t >= off) ? scn[t - off] : 0;
        __syncthreads();
        if (t < 256) scn[t] += x;
        __syncthreads();
    }
    if (t < 256) {
        int ex = scn[t] - deg[t];                 // exclusive within bucket
        cw[t] = ex;
        int node = b * 256 + t;                   // < 100096 <= array bounds
        rp[node] = bb + ex;                       // rp[100000] == N_EDGES naturally
        dinv[node] = rsqrtf(1.0f + (float)deg[t]);
    }
    __syncthreads();
    if (ecnt <= CAP_CSR) {
        for (int i = t; i < ecnt; i += 512) {
            int v = __builtin_nontemporal_load(eb + bb + i);
            int r = atomicAdd(&cw[v >> 17], 1);   // LDS return-atomic
            esl[r] = v & SRC_MASK;
        }
        __syncthreads();
        for (int i = t; i < ecnt; i += 512)
            __builtin_nontemporal_store(esl[i], es + bb + i);   // coalesced
    } else {                                      // paranoia fallback
        for (int i = t; i < ecnt; i += 512) {
            int v = eb[bb + i];
            int r = atomicAdd(&cw[v >> 17], 1);
            es[bb + r] = v & SRC_MASK;
        }
    }
}

// ---------------- dense kernels ------------------------

typedef float f4 __attribute__((ext_vector_type(4)));

// 16 nodes per block, 256 threads = 16 nodes x 16 out-features.
// h1p = fp16( (x@W1) * dinv[node] )
__global__ void __launch_bounds__(256) k_gemm1(
    const float* __restrict__ x, const float* __restrict__ W1,
    const float* __restrict__ dinv, __half* __restrict__ h1p) {
    __shared__ float w[F_IN * H_MID];   // 8 KB
    __shared__ float xs[16 * 132];      // padded rows: no 128-stride conflicts
    int t = threadIdx.x;
    for (int i = t; i < F_IN * H_MID; i += 256) w[i] = W1[i];
    int tile = blockIdx.x;              // 6250 tiles, exact
    const f4* xg = (const f4*)(x + (size_t)tile * 16 * F_IN);
    f4* xs4 = (f4*)xs;                  // row stride 33 float4
    for (int i = t; i < 512; i += 256) {
        int r = i >> 5, c4 = i & 31;
        xs4[r * 33 + c4] = __builtin_nontemporal_load(xg + r * 32 + c4);
    }
    __syncthreads();
    int node = t >> 4, j = t & 15;
    const float* xr = xs + node * 132;
    float acc = 0.f;
#pragma unroll 8
    for (int k = 0; k < F_IN; ++k) acc += xr[k] * w[k * H_MID + j];
    int g = tile * 16 + node;
    h1p[(size_t)g * H_MID + j] = __float2half(acc * dinv[g]);
}

// gather layer 1 + fused relu/bias/prescale (fp16 in, fp32 accum, fp16 out):
// r1p[n] = fp16( relu(dinv[n]*(h1p[n] + sum h1p[s]) + b1) * dinv[n] )
__global__ void __launch_bounds__(256) k_gather1(
    const int* __restrict__ rp, const int* __restrict__ es,
    const float* __restrict__ dinv, const __half* __restrict__ h1p,
    const float* __restrict__ b1, __half* __restrict__ r1p) {
    int t = threadIdx.x;
    int node = blockIdx.x * 16 + (t >> 4), j = t & 15;
    float dv = dinv[node];
    int beg = rp[node], end = rp[node + 1];
    float acc = __half2float(h1p[(size_t)node * H_MID + j]);  // self loop
    int e = beg;
    for (; e + 8 <= end; e += 8) {
        int s0 = es[e],     s1 = es[e + 1], s2 = es[e + 2], s3 = es[e + 3];
        int s4 = es[e + 4], s5 = es[e + 5], s6 = es[e + 6], s7 = es[e + 7];
        __half v0 = h1p[(size_t)s0 * H_MID + j];
        __half v1 = h1p[(size_t)s1 * H_MID + j];
        __half v2 = h1p[(size_t)s2 * H_MID + j];
        __half v3 = h1p[(size_t)s3 * H_MID + j];
        __half v4 = h1p[(size_t)s4 * H_MID + j];
        __half v5 = h1p[(size_t)s5 * H_MID + j];
        __half v6 = h1p[(size_t)s6 * H_MID + j];
        __half v7 = h1p[(size_t)s7 * H_MID + j];
        acc += __half2float(v0) + __half2float(v1) + __half2float(v2) + __half2float(v3)
             + __half2float(v4) + __half2float(v5) + __half2float(v6) + __half2float(v7);
    }
    for (; e < end; ++e) acc += __half2float(h1p[(size_t)es[e] * H_MID + j]);
    float agg1 = dv * acc;
    unsigned short o = __half_as_ushort(__float2half(fmaxf(agg1 + b1[j], 0.f) * dv));
    __builtin_nontemporal_store(o, (unsigned short*)(r1p + (size_t)node * H_MID + j));
}

// gather layer 2 + fused @W2 + b2 epilogue (LDS).
__global__ void __launch_bounds__(256) k_gather2(
    const int* __restrict__ rp, const int* __restrict__ es,
    const float* __restrict__ dinv, const __half* __restrict__ r1p,
    const float* __restrict__ W2, const float* __restrict__ b2,
    float* __restrict__ out) {
    __shared__ float w2[H_MID * C_OUT];   // 640
    __shared__ float a2[16 * 17];         // padded
    int t = threadIdx.x;
    for (int i = t; i < H_MID * C_OUT; i += 256) w2[i] = W2[i];
    int tile = blockIdx.x;
    int node = tile * 16 + (t >> 4), j = t & 15;
    float dv = dinv[node];
    int beg = rp[node], end = rp[node + 1];
    float acc = __half2float(r1p[(size_t)node * H_MID + j]);  // self loop
    int e = beg;
    for (; e + 8 <= end; e += 8) {
        int s0 = es[e],     s1 = es[e + 1], s2 = es[e + 2], s3 = es[e + 3];
        int s4 = es[e + 4], s5 = es[e + 5], s6 = es[e + 6], s7 = es[e + 7];
        __half v0 = r1p[(size_t)s0 * H_MID + j];
        __half v1 = r1p[(size_t)s1 * H_MID + j];
        __half v2 = r1p[(size_t)s2 * H_MID + j];
        __half v3 = r1p[(size_t)s3 * H_MID + j];
        __half v4 = r1p[(size_t)s4 * H_MID + j];
        __half v5 = r1p[(size_t)s5 * H_MID + j];
        __half v6 = r1p[(size_t)s6 * H_MID + j];
        __half v7 = r1p[(size_t)s7 * H_MID + j];
        acc += __half2float(v0) + __half2float(v1) + __half2float(v2) + __half2float(v3)
             + __half2float(v4) + __half2float(v5) + __half2float(v6) + __half2float(v7);
    }
    for (; e < end; ++e) acc += __half2float(r1p[(size_t)es[e] * H_MID + j]);
    a2[(t >> 4) * 17 + j] = dv * acc;
    __syncthreads();
    for (int idx = t; idx < 16 * C_OUT; idx += 256) {
        int nd = idx / C_OUT, c = idx % C_OUT;
        float s = b2[c];
#pragma unroll
        for (int jj = 0; jj < H_MID; ++jj) s += a2[nd * 17 + jj] * w2[jj * C_OUT + c];
        __builtin_nontemporal_store(s, &out[((size_t)tile * 16 + nd) * C_OUT + c]);
    }
}

extern "C" void kernel_launch(void* const* d_in, const int* in_sizes, int n_in,
                              void* d_out, int out_size, void* d_ws, size_t ws_size,
                              hipStream_t stream) {
    const float* x  = (const float*)d_in[0];
    const int*   ei = (const int*)d_in[1];     // [2, E]: row 0 = src, row 1 = dst
    const float* W1 = (const float*)d_in[2];
    const float* b1 = (const float*)d_in[3];
    const float* W2 = (const float*)d_in[4];
    const float* b2 = (const float*)d_in[5];
    float* out = (float*)d_out;

    const int* src = ei;
    const int* dst = ei + N_EDGES;

    // ws layout (4B units), ~20 MiB:
    //   rp[100352] | dinv[100352] | es[3.2M] | h1p[1.6M __half] | r1p[1.6M __half]
    // d_out (16MB) is free scratch until k_gather2 (sole writer of out):
    //   eb[3.2M] (12.8MB) | hist[153088] (0.61MB) | part[512]  ~= 13.4MB
    int* rp     = (int*)d_ws;
    float* dinv = (float*)(rp + 100352);
    int* es     = (int*)(dinv + 100352);
    __half* h1p = (__half*)(es + N_EDGES);
    __half* r1p = h1p + (size_t)N_NODES * H_MID;

    int* eb   = (int*)d_out;
    int* hist = eb + N_EDGES;
    int* part = hist + 153088;

    k_hist <<<EBLK, 1024, 0, stream>>>(dst, hist);
    k_scanA<<<NPART, 512, 0, stream>>>(hist, part);
    k_scanB<<<1, 512, 0, stream>>>(part);
    k_part <<<EBLK, 1024, 0, stream>>>(src, dst, hist, part, eb);
    k_csr  <<<NBUK, 512, 0, stream>>>(hist, part, eb, rp, dinv, es);
    k_gemm1<<<N_NODES / 16, 256, 0, stream>>>(x, W1, dinv, h1p);
    k_gather1<<<N_NODES / 16, 256, 0, stream>>>(rp, es, dinv, h1p, b1, r1p);
    k_gather2<<<N_NODES / 16, 256, 0, stream>>>(rp, es, dinv, r1p, W2, b2, out);
}